// Round 1
// baseline (347.505 us; speedup 1.0000x reference)
//
#include <hip/hip_runtime.h>
#include <hip/hip_bf16.h>
#include <cstdint>
#include <cstddef>

// Problem constants (fixed by setup_inputs)
#define NROWS_TOTAL 130320   // B*G
#define Gg 65160
#define Mm 40962
#define Dd 512
#define OUTD 128

typedef __attribute__((ext_vector_type(4))) float f32x4;
typedef __attribute__((ext_vector_type(8))) short bf16x8;

static __device__ __forceinline__ unsigned short f2bf(float x) {
  union { float f; unsigned u; } v; v.f = x;
  unsigned r = v.u + 0x7fffu + ((v.u >> 16) & 1u);
  return (unsigned short)(r >> 16);
}

// Convert + transpose W1 (f32 [512][512]) -> W1T bf16 [n][k], W2 -> W2T bf16 [n][k]
__global__ void prep_weights(const float* __restrict__ W1, const float* __restrict__ W2,
                             unsigned short* __restrict__ W1T, unsigned short* __restrict__ W2T) {
  int r = blockIdx.x;   // 0..511 = k index (row of W1/W2)
  int t = threadIdx.x;  // 0..255
  int c = t;
  W1T[c * Dd + r] = f2bf(W1[r * Dd + c]);
  c = t + 256;
  W1T[c * Dd + r] = f2bf(W1[r * Dd + c]);
  if (t < OUTD) {
    W2T[t * Dd + r] = f2bf(W2[r * OUTD + t]);
  }
}

// Fused: gather+wsum -> GEMM1(bf16 MFMA) -> +b1 -> LayerNorm -> SiLU -> GEMM2 -> +b2
// Block: 256 threads (4 waves), 64 rows. Wave w owns cols [w*128, w*128+128) in GEMM1,
// cols [w*32, w*32+32) in GEMM2.
__global__ __launch_bounds__(256, 2) void fused_decoder(
    const float* __restrict__ mesh,   // [2][M][512] f32
    const int*   __restrict__ idx,    // [G][4]
    const float* __restrict__ wgt,    // [G][4] f32
    const float* __restrict__ b1,     // [512]
    const float* __restrict__ gamma,  // [512]
    const float* __restrict__ beta,   // [512]
    const float* __restrict__ b2,     // [128]
    const unsigned short* __restrict__ W1T, // [512][512] bf16 (W1T[n][k])
    const unsigned short* __restrict__ W2T, // [128][512] bf16 (W2T[n][k])
    float* __restrict__ out)          // [130320][128] f32
{
  __shared__ unsigned short Abuf[64][520]; // A tile, later reused for H (SiLU output)
  __shared__ float psum[64][4];
  __shared__ float psq[64][4];

  const int tid  = threadIdx.x;
  const int wid  = tid >> 6;
  const int lane = tid & 63;
  const int lrow = lane & 15;   // A-row / B-col / C-col within fragment
  const int kgrp = lane >> 4;   // 0..3
  const int row0 = blockIdx.x * 64;

  // ---------- Phase 1: gather + weighted sum -> LDS (bf16) ----------
  for (int rr = 0; rr < 64; ++rr) {
    const int row = row0 + rr;
    float ax = 0.f, ay = 0.f;
    if (row < NROWS_TOTAL) {
      const int b = row / Gg;          // uniform per-iteration -> scalar ops
      const int g = row - b * Gg;
      const float* meshb = mesh + (size_t)b * Mm * Dd;
      #pragma unroll
      for (int k = 0; k < 4; ++k) {
        const int   id = idx[g * 4 + k];
        const float w  = wgt[g * 4 + k];
        const float2 v = ((const float2*)(meshb + (size_t)id * Dd))[tid];
        ax = fmaf(w, v.x, ax);
        ay = fmaf(w, v.y, ay);
      }
    }
    const unsigned pack = (unsigned)f2bf(ax) | ((unsigned)f2bf(ay) << 16);
    *(unsigned*)&Abuf[rr][tid * 2] = pack;
  }
  __syncthreads();

  // ---------- Phase 2: GEMM1 (64x512 = A[64x512] @ W1[512x512]) ----------
  f32x4 acc1[4][8];
  #pragma unroll
  for (int i = 0; i < 4; ++i)
    #pragma unroll
    for (int j = 0; j < 8; ++j)
      acc1[i][j] = (f32x4){0.f, 0.f, 0.f, 0.f};

  const int colbase1 = wid * 128;
  for (int kk = 0; kk < 16; ++kk) {
    bf16x8 a[4];
    #pragma unroll
    for (int ar = 0; ar < 4; ++ar)
      a[ar] = *(const bf16x8*)&Abuf[ar * 16 + lrow][kk * 32 + kgrp * 8];
    #pragma unroll
    for (int bc = 0; bc < 8; ++bc) {
      const int col = colbase1 + bc * 16 + lrow;
      const bf16x8 b = *(const bf16x8*)(W1T + col * Dd + kk * 32 + kgrp * 8);
      #pragma unroll
      for (int ar = 0; ar < 4; ++ar)
        acc1[ar][bc] = __builtin_amdgcn_mfma_f32_16x16x32_bf16(a[ar], b, acc1[ar][bc], 0, 0, 0);
    }
  }

  // ---------- +b1, per-row partial sums for LayerNorm ----------
  float b1c[8];
  #pragma unroll
  for (int bc = 0; bc < 8; ++bc)
    b1c[bc] = b1[colbase1 + bc * 16 + lrow];

  #pragma unroll
  for (int ar = 0; ar < 4; ++ar) {
    #pragma unroll
    for (int v = 0; v < 4; ++v) {
      float s = 0.f, q = 0.f;
      #pragma unroll
      for (int bc = 0; bc < 8; ++bc) {
        float x = acc1[ar][bc][v] + b1c[bc];
        acc1[ar][bc][v] = x;
        s += x;
        q += x * x;
      }
      #pragma unroll
      for (int off = 1; off < 16; off <<= 1) {
        s += __shfl_xor(s, off, 64);
        q += __shfl_xor(q, off, 64);
      }
      if (lrow == 0) {
        const int r = ar * 16 + kgrp * 4 + v;
        psum[r][wid] = s;
        psq[r][wid]  = q;
      }
    }
  }
  __syncthreads();  // also guarantees all waves finished reading Abuf (A)

  // ---------- LayerNorm + SiLU, write H (bf16) into Abuf ----------
  float gmc[8], btc[8];
  #pragma unroll
  for (int bc = 0; bc < 8; ++bc) {
    const int col = colbase1 + bc * 16 + lrow;
    gmc[bc] = gamma[col];
    btc[bc] = beta[col];
  }
  #pragma unroll
  for (int ar = 0; ar < 4; ++ar) {
    #pragma unroll
    for (int v = 0; v < 4; ++v) {
      const int r = ar * 16 + kgrp * 4 + v;
      const float mu  = (psum[r][0] + psum[r][1] + psum[r][2] + psum[r][3]) * (1.f / 512.f);
      const float ms  = (psq[r][0]  + psq[r][1]  + psq[r][2]  + psq[r][3])  * (1.f / 512.f);
      const float var = ms - mu * mu;
      const float rstd = rsqrtf(var + 1e-5f);
      #pragma unroll
      for (int bc = 0; bc < 8; ++bc) {
        const float x = acc1[ar][bc][v];
        const float y = (x - mu) * rstd * gmc[bc] + btc[bc];
        const float sil = y * (1.f / (1.f + __expf(-y)));
        Abuf[r][colbase1 + bc * 16 + lrow] = f2bf(sil);
      }
    }
  }
  __syncthreads();

  // ---------- Phase 3: GEMM2 (64x128 = H[64x512] @ W2[512x128]) ----------
  f32x4 acc2[4][2];
  #pragma unroll
  for (int i = 0; i < 4; ++i)
    #pragma unroll
    for (int j = 0; j < 2; ++j)
      acc2[i][j] = (f32x4){0.f, 0.f, 0.f, 0.f};

  const int colbase2 = wid * 32;
  for (int kk = 0; kk < 16; ++kk) {
    bf16x8 a[4];
    #pragma unroll
    for (int ar = 0; ar < 4; ++ar)
      a[ar] = *(const bf16x8*)&Abuf[ar * 16 + lrow][kk * 32 + kgrp * 8];
    #pragma unroll
    for (int bc = 0; bc < 2; ++bc) {
      const int col = colbase2 + bc * 16 + lrow;
      const bf16x8 b = *(const bf16x8*)(W2T + col * Dd + kk * 32 + kgrp * 8);
      #pragma unroll
      for (int ar = 0; ar < 4; ++ar)
        acc2[ar][bc] = __builtin_amdgcn_mfma_f32_16x16x32_bf16(a[ar], b, acc2[ar][bc], 0, 0, 0);
    }
  }

  // ---------- Epilogue: +b2, store f32 ----------
  float b2c[2];
  #pragma unroll
  for (int bc = 0; bc < 2; ++bc)
    b2c[bc] = b2[colbase2 + bc * 16 + lrow];

  #pragma unroll
  for (int ar = 0; ar < 4; ++ar) {
    #pragma unroll
    for (int bc = 0; bc < 2; ++bc) {
      #pragma unroll
      for (int v = 0; v < 4; ++v) {
        const int r = ar * 16 + kgrp * 4 + v;
        const int row = row0 + r;
        if (row < NROWS_TOTAL)
          out[(size_t)row * OUTD + colbase2 + bc * 16 + lrow] = acc2[ar][bc][v] + b2c[bc];
      }
    }
  }
}

extern "C" void kernel_launch(void* const* d_in, const int* in_sizes, int n_in,
                              void* d_out, int out_size, void* d_ws, size_t ws_size,
                              hipStream_t stream) {
  const float* mesh  = (const float*)d_in[0];
  const int*   idx   = (const int*)d_in[1];
  const float* wgt   = (const float*)d_in[2];
  const float* W1    = (const float*)d_in[3];
  const float* b1    = (const float*)d_in[4];
  const float* gamma = (const float*)d_in[5];
  const float* beta  = (const float*)d_in[6];
  const float* W2    = (const float*)d_in[7];
  const float* b2    = (const float*)d_in[8];
  float* out = (float*)d_out;

  unsigned short* W1T = (unsigned short*)d_ws;              // 512*512 bf16 = 512 KB
  unsigned short* W2T = W1T + 512 * 512;                    // 128*512 bf16 = 128 KB

  prep_weights<<<512, 256, 0, stream>>>(W1, W2, W1T, W2T);

  const int nblocks = (NROWS_TOTAL + 63) / 64;              // 2037
  fused_decoder<<<nblocks, 256, 0, stream>>>(mesh, idx, wgt, b1, gamma, beta, b2,
                                             W1T, W2T, out);
}